// Round 10
// baseline (378.662 us; speedup 1.0000x reference)
//
#include <hip/hip_runtime.h>
#include <stdint.h>

// ---------- sizes (fixed by setup_inputs) ----------
#define BATCH   65536
#define FIN     32        // layer-1 in
#define HID     64        // layer-1 out / layer-2 in
#define NOUT    2048      // layer-2 out
#define NC      8         // bases per element
#define NF      9         // features per element (silu + 8 bases)
#define K1      288       // FIN*NF
#define K2      576       // HID*NF

// ---------- GEMM2 tiling: 256x256, 8 waves, i8 BK=64, NBUF=4 (r4 ledger) ----------
#define BKI     64
#define KTI     9         // K2 / BKI

typedef __bf16 bf16x8 __attribute__((ext_vector_type(8)));
typedef float f32x4 __attribute__((ext_vector_type(4)));
typedef int   i32x4 __attribute__((ext_vector_type(4)));

// ---------- helpers ----------
__device__ __forceinline__ uint16_t f2bf(float f) {
    uint32_t u = __builtin_bit_cast(uint32_t, f);
    uint32_t r = (u + 0x7fffu + ((u >> 16) & 1u)) >> 16;
    return (uint16_t)r;
}
__device__ __forceinline__ float silu_f(float v) {
    return v / (1.f + __expf(-v));
}

// Closed-form uniform cubic B-spline bases. Knots g[t]=(t-3)*0.4-1, t=0..11.
__device__ __forceinline__ void bspline8u(float xv, float out[8]) {
    float s = (xv + 2.2f) * 2.5f;
    int c = (int)floorf(s);
    float gc = (float)(c - 3) * 0.4f - 1.0f;
    float u = (xv - gc) * 2.5f;
    float u1 = 1.f - u;
    float uu = u * u, u3 = uu * u;
    float w0 = u1 * u1 * u1 * (1.f / 6.f);
    float w1 = (3.f * u3 - 6.f * uu + 4.f) * (1.f / 6.f);
    float w2 = (-3.f * u3 + 3.f * uu + 3.f * u + 1.f) * (1.f / 6.f);
    float w3 = u3 * (1.f / 6.f);
#pragma unroll
    for (int t = 0; t < 8; t++) {
        int d = c - t;
        out[t] = (d == 0) ? w3 : (d == 1) ? w2 : (d == 2) ? w1 : (d == 3) ? w0 : 0.f;
    }
}

// ---------- pack kernels ----------
__global__ void pack_w1(const float* __restrict__ bw1, const float* __restrict__ sw1,
                        const float* __restrict__ ss1, uint16_t* __restrict__ w1L) {
    int idx = blockIdx.x * 256 + threadIdx.x;
    if (idx >= 64 * K1) return;
    int o = idx / K1, k = idx % K1;
    int i = k / 9, j = k % 9;
    float v = (j == 0) ? bw1[o * FIN + i]
                       : sw1[(o * FIN + i) * NC + (j - 1)] * ss1[o * FIN + i];
    w1L[idx] = f2bf(v);
}

// W2 int8: one wave per output row o; k-order = j*64 + i; per-row scale sb[o].
__global__ void pack_w2i(const float* __restrict__ bw2, const float* __restrict__ sw2,
                         const float* __restrict__ ss2, int8_t* __restrict__ w2i,
                         float* __restrict__ sb) {
    int gid = blockIdx.x * 256 + threadIdx.x;
    int o = gid >> 6, lane = gid & 63;
    float v[9];
    float mx = 1e-20f;
#pragma unroll
    for (int j = 0; j < 9; j++) {
        int k = lane * 9 + j;
        int jj = k >> 6, i = k & 63;
        v[j] = (jj == 0) ? bw2[o * HID + i]
                         : sw2[(o * HID + i) * NC + (jj - 1)] * ss2[o * HID + i];
        mx = fmaxf(mx, fabsf(v[j]));
    }
#pragma unroll
    for (int m = 1; m < 64; m <<= 1) mx = fmaxf(mx, __shfl_xor(mx, m));
    float qs = 127.f / mx;
    if (lane == 0) sb[o] = mx * (1.f / 127.f);
#pragma unroll
    for (int j = 0; j < 9; j++)
        w2i[(size_t)o * K2 + lane * 9 + j] = (int8_t)(int)rintf(v[j] * qs);
}

// ---------- fused LN + featurize1 + MFMA layer1 + featurize2 + int8 quant ----------
#define FBR    64
#define A1LD   296
#define S2BLD  592   // bytes/row of int8 stage (576 + pad, 16-aligned)
__global__ __launch_bounds__(256) void featurize(
    const float* __restrict__ x, const float* __restrict__ lnw, const float* __restrict__ lnb,
    const uint16_t* __restrict__ w1L, int8_t* __restrict__ a2i, float* __restrict__ sa) {

    __shared__ __align__(16) char fsm[75776];
    uint16_t* w1s = (uint16_t*)fsm;              // [64][296]
    uint16_t* a1s = (uint16_t*)(fsm + 37888);    // [64][296]
    int8_t*   s2b = (int8_t*)fsm;                // [64][592] bytes (phase 3)

    const int tid = threadIdx.x;
    const int wv = tid >> 6, lane = tid & 63;
    const int rowBase = blockIdx.x * FBR;

    // ---- stage W1 [64][288] -> [64][296] ----
#pragma unroll
    for (int t = 0; t < 9; ++t) {
        int idx = t * 256 + tid;
        int o = idx / 36, cc = idx % 36;
        uint4 v = *(const uint4*)(w1L + idx * 8);
        *(uint4*)&w1s[o * A1LD + cc * 8] = v;
    }

    // ---- phase 1: LN + featurize x (4 threads/row, 8 inputs each) ----
    const int prow = tid >> 2, pq = tid & 3;
    const float* xp = x + (size_t)(rowBase + prow) * FIN + pq * 8;
    float xv[8];
    *(float4*)&xv[0] = ((const float4*)xp)[0];
    *(float4*)&xv[4] = ((const float4*)xp)[1];
    float s = 0.f, s2v = 0.f;
#pragma unroll
    for (int j = 0; j < 8; j++) { s += xv[j]; s2v += xv[j] * xv[j]; }
    s += __shfl_xor(s, 1);  s2v += __shfl_xor(s2v, 1);
    s += __shfl_xor(s, 2);  s2v += __shfl_xor(s2v, 2);
    const float mu = s * (1.f / 32.f);
    const float var = s2v * (1.f / 32.f) - mu * mu;
    const float rstd = rsqrtf(var + 1e-5f);

    float wl[8], bl[8];
    *(float4*)&wl[0] = ((const float4*)(lnw + pq * 8))[0];
    *(float4*)&wl[4] = ((const float4*)(lnw + pq * 8))[1];
    *(float4*)&bl[0] = ((const float4*)(lnb + pq * 8))[0];
    *(float4*)&bl[4] = ((const float4*)(lnb + pq * 8))[1];

    __align__(16) uint16_t tmp[72];
#pragma unroll
    for (int ii = 0; ii < 8; ii++) {
        float xn = (xv[ii] - mu) * rstd * wl[ii] + bl[ii];
        tmp[ii * 9] = f2bf(silu_f(xn));
        float bs[8];
        bspline8u(xn, bs);
#pragma unroll
        for (int j = 0; j < 8; j++) tmp[ii * 9 + 1 + j] = f2bf(bs[j]);
    }
    {
        uint16_t* dst = &a1s[prow * A1LD + pq * 72];
#pragma unroll
        for (int q = 0; q < 9; q++) *(uint4*)(dst + q * 8) = *(const uint4*)&tmp[q * 8];
    }
    __syncthreads();

    // ---- phase 2: h = A1 x W1 via MFMA (bf16) ----
    f32x4 acc[4];
#pragma unroll
    for (int n = 0; n < 4; n++) acc[n] = (f32x4){0.f, 0.f, 0.f, 0.f};
    const int arow = wv * 16 + (lane & 15);
    const int koff = (lane >> 4) * 8;
#pragma unroll
    for (int ks = 0; ks < 9; ++ks) {
        bf16x8 af = *(const bf16x8*)&a1s[arow * A1LD + ks * 32 + koff];
#pragma unroll
        for (int n = 0; n < 4; n++) {
            bf16x8 bv = *(const bf16x8*)&w1s[(n * 16 + (lane & 15)) * A1LD + ks * 32 + koff];
            acc[n] = __builtin_amdgcn_mfma_f32_16x16x32_bf16(af, bv, acc[n], 0, 0, 0);
        }
    }
    __syncthreads();   // w1s/a1s dead; s2b aliases them

    // ---- phase 3a: row maxima for dynamic int8 scale ----
    const int r0 = wv * 16 + ((lane >> 4) << 2);
    const int cb = lane & 15;
    float rmax[4] = {1e-20f, 1e-20f, 1e-20f, 1e-20f};
#pragma unroll
    for (int n = 0; n < 4; n++)
#pragma unroll
        for (int r = 0; r < 4; r++) {
            float h = acc[n][r];
            float o9[9];
            o9[0] = silu_f(h);
            bspline8u(h, &o9[1]);
            float mx = fabsf(o9[0]);
#pragma unroll
            for (int j = 1; j < 9; j++) mx = fmaxf(mx, fabsf(o9[j]));
            rmax[r] = fmaxf(rmax[r], mx);
        }
#pragma unroll
    for (int m = 1; m < 16; m <<= 1)
#pragma unroll
        for (int r = 0; r < 4; r++) rmax[r] = fmaxf(rmax[r], __shfl_xor(rmax[r], m));
    float qs[4];
#pragma unroll
    for (int r = 0; r < 4; r++) qs[r] = 127.f / rmax[r];
    if (cb == 0)
#pragma unroll
        for (int r = 0; r < 4; r++) sa[rowBase + r0 + r] = rmax[r] * (1.f / 127.f);

    // ---- phase 3b: quantize into LDS stage ----
#pragma unroll
    for (int n = 0; n < 4; n++)
#pragma unroll
        for (int r = 0; r < 4; r++) {
            float h = acc[n][r];
            float o9[9];
            o9[0] = silu_f(h);
            bspline8u(h, &o9[1]);
            int8_t* op = &s2b[(r0 + r) * S2BLD + n * 16 + cb];
#pragma unroll
            for (int j = 0; j < 9; j++) op[j * 64] = (int8_t)(int)rintf(o9[j] * qs[r]);
        }
    __syncthreads();

    // ---- phase 4: coalesced flush: 64 rows x 576 B = 2304 x 16B chunks ----
#pragma unroll
    for (int q = 0; q < 9; ++q) {
        int g = q * 256 + tid;
        int row = g / 36, c = g % 36;
        uint4 v = *(const uint4*)&s2b[row * S2BLD + c * 16];
        *(uint4*)(a2i + (size_t)(rowBase + row) * K2 + c * 16) = v;
    }
}

// ---------- GEMM2 int8: (65536 x 576) x (576 x 2048) ----------
// A [M][576] i8; Bt [N][576] i8; C = i32-dot * sa[row] * sb[col].
// Exact r4 schedule, KT=9, BK=64 bytes: 256x256 tile, 8 waves (2x4),
// NBUF=4 ring, B-frag read-ahead, counted vmcnt(6/4/0) before barrier.
// Swizzle (rule 21 both-sides): LDS[row][slot16B] = G[row][slot^((row>>2)&3)].
__device__ __forceinline__ void gload16(const void* g, const void* l) {
    __builtin_amdgcn_global_load_lds(
        (const __attribute__((address_space(1))) void*)g,
        (__attribute__((address_space(3))) void*)l, 16, 0, 0);
}

__global__ __launch_bounds__(512, 2) void gemm2i(const int8_t* __restrict__ A,
                                                 const int8_t* __restrict__ Bt,
                                                 const float* __restrict__ sa,
                                                 const float* __restrict__ sb,
                                                 float* __restrict__ C) {
    __shared__ __align__(16) int8_t lds[4][2][256 * BKI];   // 128 KiB

    const int tid = threadIdx.x;
    const int wv = tid >> 6, lane = tid & 63;
    const int wr = wv >> 2, wc = wv & 3;          // 2 x 4 wave grid

    // XCD-aware bijective swizzle (2048 blocks, 2048 % 8 == 0)
    const uint32_t bid = blockIdx.x;
    const uint32_t wk = (bid & 7u) * 256u + (bid >> 3);
    const uint32_t ntile = wk & 7u, mtile = wk >> 3;

    // Staging: thread -> row tid>>2 (128 rows/line), 16B slot tid&3;
    // linear LDS dest; global source slot pre-swizzled with (row>>2)&3.
    const int srow = tid >> 2;
    const int scol = (((tid & 3) ^ ((tid >> 4) & 3)) << 4);   // bytes
    const int8_t* gA = A  + (size_t)(mtile * 256 + srow) * K2 + scol;
    const int8_t* gB = Bt + (size_t)(ntile * 256 + srow) * K2 + scol;

#define STAGE_A(b, kt) do { \
    gload16(gA + (kt) * BKI,                    &lds[b][0][wv * 1024]); \
    gload16(gA + (size_t)128 * K2 + (kt) * BKI, &lds[b][0][8192 + wv * 1024]); } while (0)
#define STAGE_B(b, kt) do { \
    gload16(gB + (kt) * BKI,                    &lds[b][1][wv * 1024]); \
    gload16(gB + (size_t)128 * K2 + (kt) * BKI, &lds[b][1][8192 + wv * 1024]); } while (0)

    // Fragment reads: row = base + (lane&15); wanted slot = lane>>4;
    // slot' = (lane>>4) ^ ((row>>2)&3) -> 2 lanes/bank-quad (free).
    const int slot16 = (((lane >> 4) ^ ((lane >> 2) & 3)) << 4);
    const int aoff = (wr * 128 + (lane & 15)) * BKI + slot16;
    const int boff = (wc * 64  + (lane & 15)) * BKI + slot16;

    i32x4 acc[8][4];
#pragma unroll
    for (int m = 0; m < 8; m++)
#pragma unroll
        for (int n = 0; n < 4; n++) acc[m][n] = (i32x4){0, 0, 0, 0};

    // Prologue: stage tiles 0,1,2 (12 loads); T0 resident after vmcnt(8).
    STAGE_A(0, 0); STAGE_B(0, 0);
    STAGE_A(1, 1); STAGE_B(1, 1);
    STAGE_A(2, 2); STAGE_B(2, 2);
    asm volatile("s_waitcnt vmcnt(8)" ::: "memory");
    asm volatile("s_barrier" ::: "memory");

    // Read-ahead: B frags of tile 0.
    i32x4 bvc[4];
#pragma unroll
    for (int n = 0; n < 4; ++n) bvc[n] = *(const i32x4*)&lds[0][1][boff + n * 1024];

#pragma unroll
    for (int t = 0; t < KTI; ++t) {
        const int b = t & 3;
        i32x4 afc[4], afB[4], bvn[4];

        // ---- phase 1: read ALL A-frags of tile t; stage A(t+3); vmcnt; barrier ----
#pragma unroll
        for (int m = 0; m < 4; ++m) afc[m] = *(const i32x4*)&lds[b][0][aoff + m * 1024];
#pragma unroll
        for (int m = 0; m < 4; ++m) afB[m] = *(const i32x4*)&lds[b][0][aoff + (m + 4) * 1024];
        if (t + 3 < KTI) STAGE_A((t + 3) & 3, t + 3);
        // Ledger: steady outstanding after wait = A(t+3),B(t+2),A(t+2) = 6.
        if (t <= KTI - 4)      asm volatile("s_waitcnt vmcnt(6)" ::: "memory");
        else if (t == KTI - 3) asm volatile("s_waitcnt vmcnt(4)" ::: "memory");
        else if (t == KTI - 2) asm volatile("s_waitcnt vmcnt(0)" ::: "memory");
        asm volatile("s_barrier" ::: "memory");

        __builtin_amdgcn_s_setprio(1);
#pragma unroll
        for (int m = 0; m < 4; ++m)
#pragma unroll
            for (int n = 0; n < 4; ++n)
                acc[m][n] = __builtin_amdgcn_mfma_i32_16x16x64_i8(afc[m], bvc[n], acc[m][n], 0, 0, 0);
        __builtin_amdgcn_s_setprio(0);
        asm volatile("s_barrier" ::: "memory");

        // ---- phase 2: read NEXT tile's B-frags (read-ahead); stage B(t+3) ----
        if (t < KTI - 1) {
#pragma unroll
            for (int n = 0; n < 4; ++n)
                bvn[n] = *(const i32x4*)&lds[(t + 1) & 3][1][boff + n * 1024];
        }
        if (t + 3 < KTI) STAGE_B((t + 3) & 3, t + 3);
        asm volatile("s_barrier" ::: "memory");

        __builtin_amdgcn_s_setprio(1);
#pragma unroll
        for (int m = 0; m < 4; ++m)
#pragma unroll
            for (int n = 0; n < 4; ++n)
                acc[m + 4][n] = __builtin_amdgcn_mfma_i32_16x16x64_i8(afB[m], bvc[n], acc[m + 4][n], 0, 0, 0);
        __builtin_amdgcn_s_setprio(0);

        if (t < KTI - 1) {
            asm volatile("s_barrier" ::: "memory");
#pragma unroll
            for (int n = 0; n < 4; ++n) bvc[n] = bvn[n];
        }
    }
#undef STAGE_A
#undef STAGE_B

    // ---- epilogue: dequant + store ----
    const int crow0 = (int)mtile * 256 + wr * 128 + ((lane >> 4) << 2);
    const int ccol0 = (int)ntile * 256 + wc * 64 + (lane & 15);
    float sbv[4];
#pragma unroll
    for (int n = 0; n < 4; ++n) sbv[n] = sb[ccol0 + n * 16];
#pragma unroll
    for (int m = 0; m < 8; ++m) {
        float sav[4];
#pragma unroll
        for (int r = 0; r < 4; ++r) sav[r] = sa[crow0 + m * 16 + r];
#pragma unroll
        for (int n = 0; n < 4; ++n) {
            float* cp = C + (size_t)(crow0 + m * 16) * NOUT + ccol0 + n * 16;
#pragma unroll
            for (int r = 0; r < 4; ++r)
                cp[(size_t)r * NOUT] = (float)acc[m][n][r] * sav[r] * sbv[n];
        }
    }
}

// ---------- launcher ----------
extern "C" void kernel_launch(void* const* d_in, const int* in_sizes, int n_in,
                              void* d_out, int out_size, void* d_ws, size_t ws_size,
                              hipStream_t stream) {
    const float* x    = (const float*)d_in[0];
    const float* lnw  = (const float*)d_in[1];
    const float* lnb  = (const float*)d_in[2];
    const float* bw1  = (const float*)d_in[3];
    const float* sw1  = (const float*)d_in[4];
    const float* ss1  = (const float*)d_in[5];
    const float* bw2  = (const float*)d_in[6];
    const float* sw2  = (const float*)d_in[7];
    const float* ss2  = (const float*)d_in[8];

    char* ws = (char*)d_ws;
    uint16_t* w1L = (uint16_t*)ws;                  // 36,864 B
    int8_t*   w2i = (int8_t*)(ws + 65536);          // 1,179,648 B
    float*    sb  = (float*)(ws + 1310720);         // 8,192 B
    float*    sa  = (float*)(ws + 1376256);         // 262,144 B
    int8_t*   a2i = (int8_t*)(ws + 1703936);        // 37,748,736 B
    float* out = (float*)d_out;

    pack_w1<<<dim3(72), dim3(256), 0, stream>>>(bw1, sw1, ss1, w1L);
    pack_w2i<<<dim3(NOUT / 4), dim3(256), 0, stream>>>(bw2, sw2, ss2, w2i, sb);
    featurize<<<dim3(BATCH / FBR), dim3(256), 0, stream>>>(x, lnw, lnb, w1L, a2i, sa);
    gemm2i<<<dim3((BATCH / 256) * (NOUT / 256)), dim3(512), 0, stream>>>(a2i, w2i, sa, sb, out);
}

// Round 11
// 300.327 us; speedup vs baseline: 1.2608x; 1.2608x over previous
//
#include <hip/hip_runtime.h>
#include <stdint.h>

// ---------- sizes (fixed by setup_inputs) ----------
#define BATCH   65536
#define FIN     32        // layer-1 in
#define HID     64        // layer-1 out / layer-2 in
#define NOUT    2048      // layer-2 out
#define NC      8         // bases per element
#define NF      9         // features per element (silu + 8 bases)
#define K1      288       // FIN*NF
#define K2      576       // HID*NF

// ---------- GEMM2 tiling: 256x256, 8 waves, BK=32, NBUF=4, 32x32x16 frags ----------
#define BK      32
#define KT      18        // K2/BK

typedef __bf16 bf16x8 __attribute__((ext_vector_type(8)));
typedef float f32x4  __attribute__((ext_vector_type(4)));
typedef float f32x16 __attribute__((ext_vector_type(16)));

// ---------- helpers ----------
__device__ __forceinline__ uint16_t f2bf(float f) {
    uint32_t u = __builtin_bit_cast(uint32_t, f);
    uint32_t r = (u + 0x7fffu + ((u >> 16) & 1u)) >> 16;
    return (uint16_t)r;
}
__device__ __forceinline__ float silu_f(float v) {
    return v / (1.f + __expf(-v));
}

// Closed-form uniform cubic B-spline bases. Knots g[t]=(t-3)*0.4-1, t=0..11.
__device__ __forceinline__ void bspline8u(float xv, float out[8]) {
    float s = (xv + 2.2f) * 2.5f;
    int c = (int)floorf(s);
    float gc = (float)(c - 3) * 0.4f - 1.0f;
    float u = (xv - gc) * 2.5f;
    float u1 = 1.f - u;
    float uu = u * u, u3 = uu * u;
    float w0 = u1 * u1 * u1 * (1.f / 6.f);
    float w1 = (3.f * u3 - 6.f * uu + 4.f) * (1.f / 6.f);
    float w2 = (-3.f * u3 + 3.f * uu + 3.f * u + 1.f) * (1.f / 6.f);
    float w3 = u3 * (1.f / 6.f);
#pragma unroll
    for (int t = 0; t < 8; t++) {
        int d = c - t;
        out[t] = (d == 0) ? w3 : (d == 1) ? w2 : (d == 2) ? w1 : (d == 3) ? w0 : 0.f;
    }
}

// ---------- pack kernels (bf16, verified r6) ----------
__global__ void pack_w1(const float* __restrict__ bw1, const float* __restrict__ sw1,
                        const float* __restrict__ ss1, uint16_t* __restrict__ w1L) {
    int idx = blockIdx.x * 256 + threadIdx.x;
    if (idx >= 64 * K1) return;
    int o = idx / K1, k = idx % K1;
    int i = k / 9, j = k % 9;
    float v = (j == 0) ? bw1[o * FIN + i]
                       : sw1[(o * FIN + i) * NC + (j - 1)] * ss1[o * FIN + i];
    w1L[idx] = f2bf(v);
}

__global__ void pack_w2(const float* __restrict__ bw2, const float* __restrict__ sw2,
                        const float* __restrict__ ss2, uint16_t* __restrict__ w2p) {
    int idx = blockIdx.x * 256 + threadIdx.x;
    if (idx >= NOUT * K2) return;
    int n = idx / K2, k = idx % K2;
    int j = k >> 6, i = k & 63;
    float v = (j == 0) ? bw2[n * HID + i]
                       : sw2[(n * HID + i) * NC + (j - 1)] * ss2[n * HID + i];
    w2p[idx] = f2bf(v);
}

// ---------- fused LN + featurize1 + MFMA layer1 + featurize2 (r6, verified) ----------
#define FBR    64
#define A1LD   296
#define S2LD   584
__global__ __launch_bounds__(256) void featurize(
    const float* __restrict__ x, const float* __restrict__ lnw, const float* __restrict__ lnb,
    const uint16_t* __restrict__ w1L, uint16_t* __restrict__ a2) {

    __shared__ __align__(16) char fsm[75776];
    uint16_t* w1s = (uint16_t*)fsm;              // [64][296]
    uint16_t* a1s = (uint16_t*)(fsm + 37888);    // [64][296]
    uint16_t* s2  = (uint16_t*)fsm;              // [64][584] (phase 3)

    const int tid = threadIdx.x;
    const int wv = tid >> 6, lane = tid & 63;
    const int rowBase = blockIdx.x * FBR;

#pragma unroll
    for (int t = 0; t < 9; ++t) {
        int idx = t * 256 + tid;
        int o = idx / 36, cc = idx % 36;
        uint4 v = *(const uint4*)(w1L + idx * 8);
        *(uint4*)&w1s[o * A1LD + cc * 8] = v;
    }

    const int prow = tid >> 2, pq = tid & 3;
    const float* xp = x + (size_t)(rowBase + prow) * FIN + pq * 8;
    float xv[8];
    *(float4*)&xv[0] = ((const float4*)xp)[0];
    *(float4*)&xv[4] = ((const float4*)xp)[1];
    float s = 0.f, s2v = 0.f;
#pragma unroll
    for (int j = 0; j < 8; j++) { s += xv[j]; s2v += xv[j] * xv[j]; }
    s += __shfl_xor(s, 1);  s2v += __shfl_xor(s2v, 1);
    s += __shfl_xor(s, 2);  s2v += __shfl_xor(s2v, 2);
    const float mu = s * (1.f / 32.f);
    const float var = s2v * (1.f / 32.f) - mu * mu;
    const float rstd = rsqrtf(var + 1e-5f);

    float wl[8], bl[8];
    *(float4*)&wl[0] = ((const float4*)(lnw + pq * 8))[0];
    *(float4*)&wl[4] = ((const float4*)(lnw + pq * 8))[1];
    *(float4*)&bl[0] = ((const float4*)(lnb + pq * 8))[0];
    *(float4*)&bl[4] = ((const float4*)(lnb + pq * 8))[1];

    __align__(16) uint16_t tmp[72];
#pragma unroll
    for (int ii = 0; ii < 8; ii++) {
        float xn = (xv[ii] - mu) * rstd * wl[ii] + bl[ii];
        tmp[ii * 9] = f2bf(silu_f(xn));
        float bs[8];
        bspline8u(xn, bs);
#pragma unroll
        for (int j = 0; j < 8; j++) tmp[ii * 9 + 1 + j] = f2bf(bs[j]);
    }
    {
        uint16_t* dst = &a1s[prow * A1LD + pq * 72];
#pragma unroll
        for (int q = 0; q < 9; q++) *(uint4*)(dst + q * 8) = *(const uint4*)&tmp[q * 8];
    }
    __syncthreads();

    f32x4 acc[4];
#pragma unroll
    for (int n = 0; n < 4; n++) acc[n] = (f32x4){0.f, 0.f, 0.f, 0.f};
    const int arow = wv * 16 + (lane & 15);
    const int koff = (lane >> 4) * 8;
#pragma unroll
    for (int ks = 0; ks < 9; ++ks) {
        bf16x8 af = *(const bf16x8*)&a1s[arow * A1LD + ks * 32 + koff];
#pragma unroll
        for (int n = 0; n < 4; n++) {
            bf16x8 bv = *(const bf16x8*)&w1s[(n * 16 + (lane & 15)) * A1LD + ks * 32 + koff];
            acc[n] = __builtin_amdgcn_mfma_f32_16x16x32_bf16(af, bv, acc[n], 0, 0, 0);
        }
    }
    __syncthreads();

    const int r0 = wv * 16 + ((lane >> 4) << 2);
    const int cb = lane & 15;
#pragma unroll
    for (int n = 0; n < 4; n++)
#pragma unroll
        for (int r = 0; r < 4; r++) {
            float h = acc[n][r];
            float o9[9];
            o9[0] = silu_f(h);
            bspline8u(h, &o9[1]);
            uint16_t* op = &s2[(size_t)(r0 + r) * S2LD + n * 16 + cb];
#pragma unroll
            for (int j = 0; j < 9; j++) op[j * 64] = f2bf(o9[j]);
        }
    __syncthreads();

#pragma unroll
    for (int q = 0; q < 18; ++q) {
        int g = q * 256 + tid;
        int row = g / 72, c = g % 72;
        uint4 v = *(const uint4*)&s2[row * S2LD + c * 8];
        *(uint4*)(a2 + (size_t)(rowBase + row) * K2 + c * 8) = v;
    }
}

// ---------- GEMM2: (65536 x 576) x (576 x 2048), 32x32x16 frags ----------
// A [M][576] bf16 row-major; Bt [N][576] bf16 row-major; C [M][N] fp32.
// 256x256 tile, 8 waves (2M x 4N, wave tile 128x64), BK=32, NBUF=4 ring.
// vs r4 (best measured): 32x32x16 MFMA (16@8cy vs 32@5cy per tile), no
// B read-ahead (12 vs 16 ds_read_b128/tile), 3 barriers/tile (vs 4).
// vmcnt ledger (2 stages/tile, 2 loads each; simulated r11):
//   prologue stages tiles 0,1,2 (12 loads), vmcnt(8) -> tile0 resident;
//   tile t P1 stages A(t+3) then vmcnt(6) -> retires A(t+1),B(t+1) ->
//   tile t+1 resident for its own P1 reads. Tail: t==15 -> 4, t==16 -> 0.
// WAR: STAGE into buf (t+3)&3 = (t-1)&3 issued after tile t-1's end barrier,
// whose reads were lgkm-drained before their MFMA (compiler).
__device__ __forceinline__ void gload16(const uint16_t* g, const uint16_t* l) {
    __builtin_amdgcn_global_load_lds(
        (const __attribute__((address_space(1))) void*)g,
        (__attribute__((address_space(3))) void*)l, 16, 0, 0);
}

__global__ __launch_bounds__(512, 2) void gemm2_kernel(const uint16_t* __restrict__ A,
                                                       const uint16_t* __restrict__ Bt,
                                                       float* __restrict__ C) {
    __shared__ __align__(16) uint16_t lds[4][2][256 * BK];   // 128 KiB

    const int tid = threadIdx.x;
    const int wv = tid >> 6, lane = tid & 63;
    const int wr = wv >> 2, wc = wv & 3;          // 2 x 4 wave grid

    // XCD-aware bijective swizzle (2048 blocks, 2048 % 8 == 0)
    const uint32_t bid = blockIdx.x;
    const uint32_t wk = (bid & 7u) * 256u + (bid >> 3);
    const uint32_t ntile = wk & 7u, mtile = wk >> 3;

    // Staging (r4-verified): thread -> row tid>>2, 16B slot tid&3; linear LDS
    // dest; global source slot pre-swizzled: slot_src = (tid&3) ^ ((row>>1)&3).
    const int srow = tid >> 2;
    const int scol = (((tid & 3) ^ ((tid >> 3) & 3)) << 3);
    const uint16_t* gA = A  + (size_t)(mtile * 256 + srow) * K2 + scol;
    const uint16_t* gB = Bt + (size_t)(ntile * 256 + srow) * K2 + scol;

#define STAGE_A(b, kt) do { \
    gload16(gA + (kt) * BK,                    &lds[b][0][wv * 512]); \
    gload16(gA + (size_t)128 * K2 + (kt) * BK, &lds[b][0][4096 + wv * 512]); } while (0)
#define STAGE_B(b, kt) do { \
    gload16(gB + (kt) * BK,                    &lds[b][1][wv * 512]); \
    gload16(gB + (size_t)128 * K2 + (kt) * BK, &lds[b][1][4096 + wv * 512]); } while (0)

    // 32x32x16 fragment reads: row = base + frag*32 + (lane&31);
    // wanted 16B slot = ks*2 + (lane>>5); slot' = wanted ^ ((row>>1)&3),
    // (row>>1)&3 == (lane>>1)&3. Bank check: 2 lanes/bank-quad (free, m136).
    const int r5 = lane & 31;
    const int kg = lane >> 5;
    const int sx = (lane >> 1) & 3;
    const int swzK0 = ((kg    ) ^ sx) << 3;      // ks=0, elem offset
    const int swzK1 = ((kg | 2) ^ sx) << 3;      // ks=1 (slot = 2 + kg)
    const int abase = (wr * 128 + r5) * BK;      // + mf*1024
    const int bbase = (wc * 64  + r5) * BK;      // + nf*1024

    f32x16 acc[4][2];
#pragma unroll
    for (int m = 0; m < 4; m++)
#pragma unroll
        for (int n = 0; n < 2; n++)
#pragma unroll
            for (int r = 0; r < 16; r++) acc[m][n][r] = 0.f;

    // Prologue: stage tiles 0,1,2 (12 loads); vmcnt(8) -> tile 0 resident.
    STAGE_A(0, 0); STAGE_B(0, 0);
    STAGE_A(1, 1); STAGE_B(1, 1);
    STAGE_A(2, 2); STAGE_B(2, 2);
    asm volatile("s_waitcnt vmcnt(8)" ::: "memory");
    asm volatile("s_barrier" ::: "memory");

#pragma unroll
    for (int t = 0; t < KT; ++t) {
        const int b = t & 3;
        const uint16_t* As = &lds[b][0][0];
        const uint16_t* Bs = &lds[b][1][0];
        bf16x8 bv[2][2], af[2][2], ag[2][2];

        // ---- P1: read B frags + A frags m0,m1; stage A(t+3); vmcnt; barrier ----
#pragma unroll
        for (int n = 0; n < 2; ++n) {
            bv[n][0] = *(const bf16x8*)&Bs[bbase + n * 1024 + swzK0];
            bv[n][1] = *(const bf16x8*)&Bs[bbase + n * 1024 + swzK1];
        }
#pragma unroll
        for (int m = 0; m < 2; ++m) {
            af[m][0] = *(const bf16x8*)&As[abase + m * 1024 + swzK0];
            af[m][1] = *(const bf16x8*)&As[abase + m * 1024 + swzK1];
        }
        if (t + 3 < KT) STAGE_A((t + 3) & 3, t + 3);
        if (t <= KT - 4)      asm volatile("s_waitcnt vmcnt(6)" ::: "memory");
        else if (t == KT - 3) asm volatile("s_waitcnt vmcnt(4)" ::: "memory");
        else if (t == KT - 2) asm volatile("s_waitcnt vmcnt(0)" ::: "memory");
        asm volatile("s_barrier" ::: "memory");

        __builtin_amdgcn_s_setprio(1);
#pragma unroll
        for (int m = 0; m < 2; ++m)
#pragma unroll
            for (int n = 0; n < 2; ++n)
#pragma unroll
                for (int ks = 0; ks < 2; ++ks)
                    acc[m][n] = __builtin_amdgcn_mfma_f32_32x32x16_bf16(af[m][ks], bv[n][ks], acc[m][n], 0, 0, 0);
        __builtin_amdgcn_s_setprio(0);
        asm volatile("s_barrier" ::: "memory");

        // ---- P2: read A frags m2,m3; stage B(t+3); MFMA; end barrier ----
#pragma unroll
        for (int m = 0; m < 2; ++m) {
            ag[m][0] = *(const bf16x8*)&As[abase + (m + 2) * 1024 + swzK0];
            ag[m][1] = *(const bf16x8*)&As[abase + (m + 2) * 1024 + swzK1];
        }
        if (t + 3 < KT) STAGE_B((t + 3) & 3, t + 3);
        __builtin_amdgcn_s_setprio(1);
#pragma unroll
        for (int m = 0; m < 2; ++m)
#pragma unroll
            for (int n = 0; n < 2; ++n)
#pragma unroll
                for (int ks = 0; ks < 2; ++ks)
                    acc[m + 2][n] = __builtin_amdgcn_mfma_f32_32x32x16_bf16(ag[m][ks], bv[n][ks], acc[m + 2][n], 0, 0, 0);
        __builtin_amdgcn_s_setprio(0);
        if (t < KT - 1) asm volatile("s_barrier" ::: "memory");
    }
#undef STAGE_A
#undef STAGE_B

    // ---- epilogue: C/D layout (m74/m101): col=lane&31,
    // row = (reg&3) + 8*(reg>>2) + 4*(lane>>5) ----
    const int ccolb = (int)ntile * 256 + wc * 64 + r5;
    const int crowb = (int)mtile * 256 + wr * 128 + 4 * kg;
#pragma unroll
    for (int m = 0; m < 4; ++m)
#pragma unroll
        for (int n = 0; n < 2; ++n) {
            float* cp = C + (size_t)(crowb + m * 32) * NOUT + ccolb + n * 32;
#pragma unroll
            for (int r = 0; r < 16; ++r)
                cp[(size_t)((r & 3) + 8 * (r >> 2)) * NOUT] = acc[m][n][r];
        }
}

// ---------- launcher ----------
extern "C" void kernel_launch(void* const* d_in, const int* in_sizes, int n_in,
                              void* d_out, int out_size, void* d_ws, size_t ws_size,
                              hipStream_t stream) {
    const float* x    = (const float*)d_in[0];
    const float* lnw  = (const float*)d_in[1];
    const float* lnb  = (const float*)d_in[2];
    const float* bw1  = (const float*)d_in[3];
    const float* sw1  = (const float*)d_in[4];
    const float* ss1  = (const float*)d_in[5];
    const float* bw2  = (const float*)d_in[6];
    const float* sw2  = (const float*)d_in[7];
    const float* ss2  = (const float*)d_in[8];

    char* ws = (char*)d_ws;
    uint16_t* w1L = (uint16_t*)ws;                          // 36,864 B
    uint16_t* w2p = (uint16_t*)(ws + 65536);                // 2,359,296 B
    uint16_t* a2  = (uint16_t*)(ws + 65536 + 2359296);      // 75,497,472 B
    float* out = (float*)d_out;

    pack_w1<<<dim3(72), dim3(256), 0, stream>>>(bw1, sw1, ss1, w1L);
    pack_w2<<<dim3((NOUT * K2 + 255) / 256), dim3(256), 0, stream>>>(bw2, sw2, ss2, w2p);
    featurize<<<dim3(BATCH / FBR), dim3(256), 0, stream>>>(x, lnw, lnb, w1L, a2);
    gemm2_kernel<<<dim3((BATCH / 256) * (NOUT / 256)), dim3(512), 0, stream>>>(a2, w2p, out);
}